// Round 1
// baseline (787.700 us; speedup 1.0000x reference)
//
#include <hip/hip_runtime.h>
#include <float.h>

#define DIMD   128
#define KCODES 1024
#define NROWS  65536

// ---------------- embed row norms: |e_k|^2 ----------------
__global__ void enorm_kernel(const float* __restrict__ embed, float* __restrict__ enorm) {
    int k = blockIdx.x * blockDim.x + threadIdx.x;
    if (k < KCODES) {
        const float4* e = (const float4*)(embed + (size_t)k * DIMD);
        float s = 0.f;
#pragma unroll
        for (int c = 0; c < DIMD / 4; ++c) {
            float4 v = e[c];
            s += v.x * v.x + v.y * v.y + v.z * v.z + v.w * v.w;
        }
        enorm[k] = s;
    }
}

// ---------------- argmin over codes (tiled fp32 GEMM + running min) ----------------
// BM=64 rows x BN=64 codes per chunk, 16 chunks, 256 threads, 4x4 microtile.
#define BM 64
#define BN 64
#define TM 4
#define TN 4
#define LDP (DIMD + 4)   // pad leading dim to break power-of-2 bank stride

__global__ __launch_bounds__(256) void argmin_kernel(
    const float* __restrict__ x, const float* __restrict__ embed,
    const float* __restrict__ enorm, int* __restrict__ ind_i, float* __restrict__ ind_f)
{
    __shared__ float As[BM][LDP];
    __shared__ float Bs[BN][LDP];
    __shared__ float xx[BM];
    __shared__ float ee[BN];
    __shared__ float redv[BM][16];
    __shared__ int   redi[BM][16];

    const int tid = threadIdx.x;
    const int tx = tid & 15;        // code-tile coord (cols)
    const int ty = tid >> 4;        // row-tile coord
    const int row0 = blockIdx.x * BM;

    // Load A tile (64 rows x 128), coalesced float4
    for (int i = tid; i < BM * (DIMD / 4); i += 256) {
        int r = i >> 5;       // /32
        int c = i & 31;
        float4 v = ((const float4*)(x + (size_t)(row0 + r) * DIMD))[c];
        *(float4*)&As[r][c * 4] = v;
    }
    __syncthreads();

    // per-row |x|^2 (threads 0..63)
    if (tid < BM) {
        float s = 0.f;
#pragma unroll 8
        for (int c = 0; c < DIMD; c += 4) {
            float4 v = *(float4*)&As[tid][c];
            s += v.x * v.x + v.y * v.y + v.z * v.z + v.w * v.w;
        }
        xx[tid] = s;
    }

    float bestv[TM];
    int   besti[TM];
#pragma unroll
    for (int r = 0; r < TM; ++r) { bestv[r] = FLT_MAX; besti[r] = 0; }

    for (int chunk = 0; chunk < KCODES / BN; ++chunk) {
        const int col0 = chunk * BN;
        __syncthreads();   // previous chunk's Bs reads done (also orders xx writes before use)
        for (int i = tid; i < BN * (DIMD / 4); i += 256) {
            int r = i >> 5;
            int c = i & 31;
            *(float4*)&Bs[r][c * 4] = ((const float4*)(embed + (size_t)(col0 + r) * DIMD))[c];
        }
        if (tid < BN) ee[tid] = enorm[col0 + tid];
        __syncthreads();

        float acc[TM][TN] = {};
#pragma unroll 8
        for (int k = 0; k < DIMD; k += 4) {
            float4 a[TM], b[TN];
#pragma unroll
            for (int r = 0; r < TM; ++r) a[r] = *(float4*)&As[ty * TM + r][k];
#pragma unroll
            for (int c = 0; c < TN; ++c) b[c] = *(float4*)&Bs[tx * TN + c][k];
#pragma unroll
            for (int r = 0; r < TM; ++r)
#pragma unroll
                for (int c = 0; c < TN; ++c)
                    acc[r][c] += a[r].x * b[c].x + a[r].y * b[c].y +
                                 a[r].z * b[c].z + a[r].w * b[c].w;
        }

#pragma unroll
        for (int r = 0; r < TM; ++r) {
            float xr = xx[ty * TM + r];
#pragma unroll
            for (int c = 0; c < TN; ++c) {
                // match reference association: (|x|^2 - 2*dot) + |e|^2
                float d = (xr - 2.0f * acc[r][c]) + ee[tx * TN + c];
                int idx = col0 + tx * TN + c;
                if (d < bestv[r] || (d == bestv[r] && idx < besti[r])) {
                    bestv[r] = d; besti[r] = idx;
                }
            }
        }
    }

    // reduce across the 16 col-thread groups per row
#pragma unroll
    for (int r = 0; r < TM; ++r) {
        redv[ty * TM + r][tx] = bestv[r];
        redi[ty * TM + r][tx] = besti[r];
    }
    __syncthreads();
    if (tid < BM) {
        float bv = redv[tid][0];
        int   bi = redi[tid][0];
#pragma unroll
        for (int j = 1; j < 16; ++j) {
            float v = redv[tid][j];
            int   ii = redi[tid][j];
            if (v < bv || (v == bv && ii < bi)) { bv = v; bi = ii; }
        }
        int row = row0 + tid;
        ind_i[row] = bi;
        ind_f[row] = (float)bi;
    }
}

// ---------------- gather quantize + scatter segment sums ----------------
__global__ __launch_bounds__(256) void scatter_kernel(
    const float* __restrict__ x, const float* __restrict__ embed,
    const int* __restrict__ ind, float* __restrict__ out_q,
    float* __restrict__ counts, float* __restrict__ embed_sum)
{
    const int tid = threadIdx.x;
    const int row = blockIdx.x * 8 + (tid >> 5);
    const int c = tid & 31;
    const int k = ind[row];

    float4 e = *(const float4*)(embed + (size_t)k * DIMD + c * 4);
    *(float4*)(out_q + (size_t)row * DIMD + c * 4) = e;

    float4 xv = *(const float4*)(x + (size_t)row * DIMD + c * 4);
    float* dst = embed_sum + (size_t)k * DIMD + c * 4;
    atomicAdd(dst + 0, xv.x);
    atomicAdd(dst + 1, xv.y);
    atomicAdd(dst + 2, xv.z);
    atomicAdd(dst + 3, xv.w);
    if (c == 0) atomicAdd(&counts[k], 1.0f);
}

// ---------------- cluster_size EMA + total + smoothed ----------------
__global__ __launch_bounds__(1024) void cluster_kernel(
    const float* __restrict__ cluster_size, const float* __restrict__ counts,
    float* __restrict__ out_cs, float* __restrict__ smoothed)
{
    __shared__ float red[1024];
    const int t = threadIdx.x;
    float cs = cluster_size[t] * 0.99f + counts[t] * 0.01f;
    out_cs[t] = cs;
    red[t] = cs;
    __syncthreads();
    for (int s = 512; s > 0; s >>= 1) {
        if (t < s) red[t] += red[t + s];
        __syncthreads();
    }
    float total = red[0];
    smoothed[t] = (cs + 1e-6f) / (total + 1e-6f * (float)KCODES) * total;
}

// ---------------- embed_avg EMA + embed_new ----------------
__global__ void embed_kernel(
    const float* __restrict__ embed_avg, const float* __restrict__ embed_sum,
    const float* __restrict__ smoothed, float* __restrict__ out_ea,
    float* __restrict__ out_en)
{
    int i = blockIdx.x * blockDim.x + threadIdx.x;
    if (i < KCODES * DIMD) {
        float ea = embed_avg[i] * 0.99f + embed_sum[i] * 0.01f;
        out_ea[i] = ea;
        out_en[i] = ea / smoothed[i >> 7];
    }
}

extern "C" void kernel_launch(void* const* d_in, const int* in_sizes, int n_in,
                              void* d_out, int out_size, void* d_ws, size_t ws_size,
                              hipStream_t stream) {
    const float* x            = (const float*)d_in[0];
    const float* embed        = (const float*)d_in[1];
    const float* cluster_size = (const float*)d_in[2];
    const float* embed_avg    = (const float*)d_in[3];

    float* out     = (float*)d_out;
    float* out_q   = out;                       // [65536*128]
    float* out_ind = out + 8388608;             // [65536]
    float* out_cs  = out + 8454144;             // [1024]
    float* out_ea  = out + 8455168;             // [1024*128]
    float* out_en  = out + 8586240;             // [1024*128]

    char* ws = (char*)d_ws;
    int*   ind_i     = (int*)ws;                // 262144 B
    float* enorm     = (float*)(ws + 262144);   // 4096 B
    float* counts    = (float*)(ws + 266240);   // 4096 B
    float* embed_sum = (float*)(ws + 270336);   // 524288 B
    float* smoothed  = (float*)(ws + 794624);   // 4096 B

    // zero counts + embed_sum (contiguous region)
    hipMemsetAsync(counts, 0, 4096 + 524288, stream);

    enorm_kernel<<<4, 256, 0, stream>>>(embed, enorm);
    argmin_kernel<<<NROWS / BM, 256, 0, stream>>>(x, embed, enorm, ind_i, out_ind);
    scatter_kernel<<<NROWS / 8, 256, 0, stream>>>(x, embed, ind_i, out_q, counts, embed_sum);
    cluster_kernel<<<1, 1024, 0, stream>>>(cluster_size, counts, out_cs, smoothed);
    embed_kernel<<<(KCODES * DIMD + 255) / 256, 256, 0, stream>>>(
        embed_avg, embed_sum, smoothed, out_ea, out_en);
}

// Round 2
// 527.112 us; speedup vs baseline: 1.4944x; 1.4944x over previous
//
#include <hip/hip_runtime.h>
#include <float.h>

#define DIMD   128
#define KCODES 1024
#define NROWS  65536
#define TAU    0.05f

typedef __attribute__((ext_vector_type(8)))  short short8;
typedef __attribute__((ext_vector_type(16))) float f32x16;

union U8 { uint4 u; short8 s; };

// round-to-nearest-even float -> bf16 (as uint16 in low bits)
__device__ __forceinline__ unsigned bfr(float f) {
    unsigned u = __float_as_uint(f);
    return (u + 0x7fffu + ((u >> 16) & 1u)) >> 16;
}

// ---------------- embed row norms: |e_k|^2 ----------------
__global__ void enorm_kernel(const float* __restrict__ embed, float* __restrict__ enorm) {
    int k = blockIdx.x * blockDim.x + threadIdx.x;
    if (k < KCODES) {
        const float4* e = (const float4*)(embed + (size_t)k * DIMD);
        float s = 0.f;
#pragma unroll
        for (int c = 0; c < DIMD / 4; ++c) {
            float4 v = e[c];
            s += v.x * v.x + v.y * v.y + v.z * v.z + v.w * v.w;
        }
        enorm[k] = s;
    }
}

// ---------------- pre-convert codebook to fragment-major bf16 hi/lo ----------------
// entry t = chunk*512 + s*64 + L : 8 bf16 = embed[chunk*32 + (L&31)][s*16 + (L>>5)*8 + j]
__global__ __launch_bounds__(256) void preconvert_kernel(
    const float* __restrict__ embed, uint4* __restrict__ ehg, uint4* __restrict__ elg)
{
    int t = blockIdx.x * 256 + threadIdx.x;     // 0..16383
    int chunk = t >> 9;
    int s = (t >> 6) & 7;
    int L = t & 63;
    const float* src = embed + ((size_t)(chunk * 32 + (L & 31)) * DIMD) + s * 16 + (L >> 5) * 8;
    float4 a = *(const float4*)src;
    float4 b = *(const float4*)(src + 4);
    float f[8] = {a.x, a.y, a.z, a.w, b.x, b.y, b.z, b.w};
    unsigned hi[8], lo[8];
#pragma unroll
    for (int j = 0; j < 8; ++j) {
        hi[j] = bfr(f[j]);
        float hf = __uint_as_float(hi[j] << 16);
        lo[j] = bfr(f[j] - hf);
    }
    uint4 H, Lw;
    H.x = hi[0] | (hi[1] << 16); H.y = hi[2] | (hi[3] << 16);
    H.z = hi[4] | (hi[5] << 16); H.w = hi[6] | (hi[7] << 16);
    Lw.x = lo[0] | (lo[1] << 16); Lw.y = lo[2] | (lo[3] << 16);
    Lw.z = lo[4] | (lo[5] << 16); Lw.w = lo[6] | (lo[7] << 16);
    ehg[t] = H;
    elg[t] = Lw;
}

// ---------------- fused MFMA distance + argmin (top-2 tracked) ----------------
__global__ __launch_bounds__(256, 2) void argmin_mfma(
    const float* __restrict__ x, const uint4* __restrict__ ehg, const uint4* __restrict__ elg,
    const float* __restrict__ enorm, int* __restrict__ ind_i, float* __restrict__ ind_f,
    int* __restrict__ wl, int* __restrict__ wl_cnt)
{
    __shared__ uint4 Bs[1024];    // [0..511] = eh chunk frags, [512..1023] = el chunk frags

    const int tid  = threadIdx.x;
    const int wave = tid >> 6;
    const int lane = tid & 63;
    const int n    = lane & 31;
    const int h    = lane >> 5;
    const int row0 = blockIdx.x * 128;
    const int rowA = row0 + wave * 32 + n;

    // ---- load + split-convert A fragments for all 8 k-steps (held in regs) ----
    uint4 xh[8], xl[8];
    const float* xrow = x + (size_t)rowA * DIMD + h * 8;
#pragma unroll
    for (int s = 0; s < 8; ++s) {
        float4 a = *(const float4*)(xrow + s * 16);
        float4 b = *(const float4*)(xrow + s * 16 + 4);
        float f[8] = {a.x, a.y, a.z, a.w, b.x, b.y, b.z, b.w};
        unsigned hi[8], lo[8];
#pragma unroll
        for (int j = 0; j < 8; ++j) {
            hi[j] = bfr(f[j]);
            float hf = __uint_as_float(hi[j] << 16);
            lo[j] = bfr(f[j] - hf);
        }
        xh[s].x = hi[0] | (hi[1] << 16); xh[s].y = hi[2] | (hi[3] << 16);
        xh[s].z = hi[4] | (hi[5] << 16); xh[s].w = hi[6] | (hi[7] << 16);
        xl[s].x = lo[0] | (lo[1] << 16); xl[s].y = lo[2] | (lo[3] << 16);
        xl[s].z = lo[4] | (lo[5] << 16); xl[s].w = lo[6] | (lo[7] << 16);
    }

    float bestv[16], best2[16];
    int   besti[16];
#pragma unroll
    for (int r = 0; r < 16; ++r) { bestv[r] = FLT_MAX; best2[r] = FLT_MAX; besti[r] = 0; }

    for (int chunk = 0; chunk < KCODES / 32; ++chunk) {
        __syncthreads();
        // stage B frags (eh + el) for 32 codes: 16 KB
        {
            const uint4* sh = ehg + chunk * 512;
            const uint4* sl = elg + chunk * 512;
#pragma unroll
            for (int i = 0; i < 2; ++i) {
                int idx = tid + i * 256;
                Bs[idx]       = sh[idx];
                Bs[512 + idx] = sl[idx];
            }
        }
        float ee_val = enorm[chunk * 32 + n];
        __syncthreads();

        f32x16 acc;
#pragma unroll
        for (int r = 0; r < 16; ++r) acc[r] = 0.f;

#pragma unroll
        for (int s = 0; s < 8; ++s) {
            U8 ah, al, bh, bl;
            ah.u = xh[s]; al.u = xl[s];
            bh.u = Bs[s * 64 + lane];
            bl.u = Bs[512 + s * 64 + lane];
            acc = __builtin_amdgcn_mfma_f32_32x32x16_bf16(ah.s, bh.s, acc, 0, 0, 0);
            acc = __builtin_amdgcn_mfma_f32_32x32x16_bf16(ah.s, bl.s, acc, 0, 0, 0);
            acc = __builtin_amdgcn_mfma_f32_32x32x16_bf16(al.s, bh.s, acc, 0, 0, 0);
        }

        const int nglob = chunk * 32 + n;
#pragma unroll
        for (int r = 0; r < 16; ++r) {
            float d = fmaf(-2.f, acc[r], ee_val);
            bool c1 = d < bestv[r];
            float t = c1 ? bestv[r] : d;
            best2[r] = fminf(best2[r], t);
            besti[r] = c1 ? nglob : besti[r];
            bestv[r] = fminf(bestv[r], d);
        }
    }

    // ---- cross-lane (32 columns) top-2 merge via butterfly ----
#pragma unroll
    for (int m = 1; m <= 16; m <<= 1) {
#pragma unroll
        for (int r = 0; r < 16; ++r) {
            float ov = __shfl_xor(bestv[r], m, 64);
            float o2 = __shfl_xor(best2[r], m, 64);
            int   oi = __shfl_xor(besti[r], m, 64);
            float hi = fmaxf(bestv[r], ov);
            best2[r] = fminf(fminf(best2[r], o2), hi);
            bool take = (ov < bestv[r]) || (ov == bestv[r] && oi < besti[r]);
            bestv[r] = take ? ov : bestv[r];
            besti[r] = take ? oi : besti[r];
        }
    }

    if (n == 0) {
#pragma unroll
        for (int r = 0; r < 16; ++r) {
            int row = row0 + wave * 32 + (r & 3) + 8 * (r >> 2) + 4 * h;
            ind_i[row] = besti[r];
            ind_f[row] = (float)besti[r];
            if (best2[r] - bestv[r] < TAU) {
                int p = atomicAdd(wl_cnt, 1);
                wl[p] = row;
            }
        }
    }
}

// ---------------- exact fp32 re-check for near-tie rows ----------------
__global__ __launch_bounds__(256) void recheck_kernel(
    const float* __restrict__ x, const float* __restrict__ embed,
    const float* __restrict__ enorm, const int* __restrict__ wl,
    const int* __restrict__ wl_cnt, int* __restrict__ ind_i, float* __restrict__ ind_f)
{
    __shared__ float xs[DIMD];
    __shared__ float rv[256];
    __shared__ int   ri[256];
    const int tid = threadIdx.x;
    const int count = *wl_cnt;

    for (int i = blockIdx.x; i < count; i += gridDim.x) {
        const int row = wl[i];
        __syncthreads();
        if (tid < DIMD) xs[tid] = x[(size_t)row * DIMD + tid];
        __syncthreads();

        const float4* xs4 = (const float4*)xs;
        float xn = 0.f;
#pragma unroll 8
        for (int c = 0; c < 32; ++c) {
            float4 v = xs4[c];
            xn += v.x * v.x + v.y * v.y + v.z * v.z + v.w * v.w;
        }

        float bv = FLT_MAX; int bi = 0;
#pragma unroll
        for (int c = 0; c < 4; ++c) {
            int code = tid * 4 + c;
            const float4* er = (const float4*)(embed + (size_t)code * DIMD);
            float acc = 0.f;
#pragma unroll 8
            for (int kk = 0; kk < 32; ++kk) {
                float4 a = xs4[kk];
                float4 b = er[kk];
                acc += a.x * b.x + a.y * b.y + a.z * b.z + a.w * b.w;
            }
            float d = (xn - 2.0f * acc) + enorm[code];
            if (d < bv) { bv = d; bi = code; }
        }
        rv[tid] = bv; ri[tid] = bi;
        __syncthreads();
        for (int s = 128; s > 0; s >>= 1) {
            if (tid < s) {
                if (rv[tid + s] < rv[tid] || (rv[tid + s] == rv[tid] && ri[tid + s] < ri[tid])) {
                    rv[tid] = rv[tid + s]; ri[tid] = ri[tid + s];
                }
            }
            __syncthreads();
        }
        if (tid == 0) { ind_i[row] = ri[0]; ind_f[row] = (float)ri[0]; }
    }
}

// ---------------- gather quantize + scatter segment sums ----------------
__global__ __launch_bounds__(256) void scatter_kernel(
    const float* __restrict__ x, const float* __restrict__ embed,
    const int* __restrict__ ind, float* __restrict__ out_q,
    float* __restrict__ counts, float* __restrict__ embed_sum)
{
    const int tid = threadIdx.x;
    const int row = blockIdx.x * 8 + (tid >> 5);
    const int c = tid & 31;
    const int k = ind[row];

    float4 e = *(const float4*)(embed + (size_t)k * DIMD + c * 4);
    *(float4*)(out_q + (size_t)row * DIMD + c * 4) = e;

    float4 xv = *(const float4*)(x + (size_t)row * DIMD + c * 4);
    float* dst = embed_sum + (size_t)k * DIMD + c * 4;
    atomicAdd(dst + 0, xv.x);
    atomicAdd(dst + 1, xv.y);
    atomicAdd(dst + 2, xv.z);
    atomicAdd(dst + 3, xv.w);
    if (c == 0) atomicAdd(&counts[k], 1.0f);
}

// ---------------- cluster_size EMA + total + smoothed ----------------
__global__ __launch_bounds__(1024) void cluster_kernel(
    const float* __restrict__ cluster_size, const float* __restrict__ counts,
    float* __restrict__ out_cs, float* __restrict__ smoothed)
{
    __shared__ float red[1024];
    const int t = threadIdx.x;
    float cs = cluster_size[t] * 0.99f + counts[t] * 0.01f;
    out_cs[t] = cs;
    red[t] = cs;
    __syncthreads();
    for (int s = 512; s > 0; s >>= 1) {
        if (t < s) red[t] += red[t + s];
        __syncthreads();
    }
    float total = red[0];
    smoothed[t] = (cs + 1e-6f) / (total + 1e-6f * (float)KCODES) * total;
}

// ---------------- embed_avg EMA + embed_new ----------------
__global__ void embed_kernel(
    const float* __restrict__ embed_avg, const float* __restrict__ embed_sum,
    const float* __restrict__ smoothed, float* __restrict__ out_ea,
    float* __restrict__ out_en)
{
    int i = blockIdx.x * blockDim.x + threadIdx.x;
    if (i < KCODES * DIMD) {
        float ea = embed_avg[i] * 0.99f + embed_sum[i] * 0.01f;
        out_ea[i] = ea;
        out_en[i] = ea / smoothed[i >> 7];
    }
}

extern "C" void kernel_launch(void* const* d_in, const int* in_sizes, int n_in,
                              void* d_out, int out_size, void* d_ws, size_t ws_size,
                              hipStream_t stream) {
    const float* x            = (const float*)d_in[0];
    const float* embed        = (const float*)d_in[1];
    const float* cluster_size = (const float*)d_in[2];
    const float* embed_avg    = (const float*)d_in[3];

    float* out     = (float*)d_out;
    float* out_q   = out;                       // [65536*128]
    float* out_ind = out + 8388608;             // [65536]
    float* out_cs  = out + 8454144;             // [1024]
    float* out_ea  = out + 8455168;             // [1024*128]
    float* out_en  = out + 8586240;             // [1024*128]

    char* ws = (char*)d_ws;
    int*   ind_i     = (int*)(ws + 0);          // 262144 B
    float* enorm     = (float*)(ws + 262144);   // 4096 B
    float* counts    = (float*)(ws + 266240);   // 4096 B
    float* embed_sum = (float*)(ws + 270336);   // 524288 B
    int*   wl_cnt    = (int*)(ws + 794624);     // 4096 B
    int*   wl        = (int*)(ws + 798720);     // 262144 B
    uint4* ehg       = (uint4*)(ws + 1060864);  // 262144 B
    uint4* elg       = (uint4*)(ws + 1323008);  // 262144 B
    float* smoothed  = (float*)(ws + 1585152);  // 4096 B

    // zero counts + embed_sum + wl_cnt (contiguous region)
    hipMemsetAsync(counts, 0, 4096 + 524288 + 4096, stream);

    enorm_kernel<<<4, 256, 0, stream>>>(embed, enorm);
    preconvert_kernel<<<64, 256, 0, stream>>>(embed, ehg, elg);
    argmin_mfma<<<NROWS / 128, 256, 0, stream>>>(x, ehg, elg, enorm, ind_i, out_ind, wl, wl_cnt);
    recheck_kernel<<<256, 256, 0, stream>>>(x, embed, enorm, wl, wl_cnt, ind_i, out_ind);
    scatter_kernel<<<NROWS / 8, 256, 0, stream>>>(x, embed, ind_i, out_q, counts, embed_sum);
    cluster_kernel<<<1, 1024, 0, stream>>>(cluster_size, counts, out_cs, smoothed);
    embed_kernel<<<(KCODES * DIMD + 255) / 256, 256, 0, stream>>>(
        embed_avg, embed_sum, smoothed, out_ea, out_en);
}

// Round 3
// 405.762 us; speedup vs baseline: 1.9413x; 1.2991x over previous
//
#include <hip/hip_runtime.h>
#include <float.h>

#define DIMD   128
#define KCODES 1024
#define NROWS  65536
#define TAU    0.05f

typedef __attribute__((ext_vector_type(8)))  short short8;
typedef __attribute__((ext_vector_type(16))) float f32x16;

union U8 { uint4 u; short8 s; };

// round-to-nearest-even float -> bf16 (as uint16 in low bits)
__device__ __forceinline__ unsigned bfr(float f) {
    unsigned u = __float_as_uint(f);
    return (u + 0x7fffu + ((u >> 16) & 1u)) >> 16;
}

// ---------------- embed row norms: |e_k|^2 ----------------
__global__ void enorm_kernel(const float* __restrict__ embed, float* __restrict__ enorm) {
    int k = blockIdx.x * blockDim.x + threadIdx.x;
    if (k < KCODES) {
        const float4* e = (const float4*)(embed + (size_t)k * DIMD);
        float s = 0.f;
#pragma unroll
        for (int c = 0; c < DIMD / 4; ++c) {
            float4 v = e[c];
            s += v.x * v.x + v.y * v.y + v.z * v.z + v.w * v.w;
        }
        enorm[k] = s;
    }
}

// ---------------- pre-convert codebook to fragment-major bf16 hi/lo ----------------
__global__ __launch_bounds__(256) void preconvert_kernel(
    const float* __restrict__ embed, uint4* __restrict__ ehg, uint4* __restrict__ elg)
{
    int t = blockIdx.x * 256 + threadIdx.x;     // 0..16383
    int chunk = t >> 9;
    int s = (t >> 6) & 7;
    int L = t & 63;
    const float* src = embed + ((size_t)(chunk * 32 + (L & 31)) * DIMD) + s * 16 + (L >> 5) * 8;
    float4 a = *(const float4*)src;
    float4 b = *(const float4*)(src + 4);
    float f[8] = {a.x, a.y, a.z, a.w, b.x, b.y, b.z, b.w};
    unsigned hi[8], lo[8];
#pragma unroll
    for (int j = 0; j < 8; ++j) {
        hi[j] = bfr(f[j]);
        float hf = __uint_as_float(hi[j] << 16);
        lo[j] = bfr(f[j] - hf);
    }
    uint4 H, Lw;
    H.x = hi[0] | (hi[1] << 16); H.y = hi[2] | (hi[3] << 16);
    H.z = hi[4] | (hi[5] << 16); H.w = hi[6] | (hi[7] << 16);
    Lw.x = lo[0] | (lo[1] << 16); Lw.y = lo[2] | (lo[3] << 16);
    Lw.z = lo[4] | (lo[5] << 16); Lw.w = lo[6] | (lo[7] << 16);
    ehg[t] = H;
    elg[t] = Lw;
}

// ---------------- fused MFMA distance + argmin (top-2 tracked) ----------------
__global__ __launch_bounds__(256, 2) void argmin_mfma(
    const float* __restrict__ x, const uint4* __restrict__ ehg, const uint4* __restrict__ elg,
    const float* __restrict__ enorm, int* __restrict__ ind_i, float* __restrict__ ind_f,
    int* __restrict__ wl, int* __restrict__ wl_cnt)
{
    __shared__ uint4 Bs[1024];

    const int tid  = threadIdx.x;
    const int wave = tid >> 6;
    const int lane = tid & 63;
    const int n    = lane & 31;
    const int h    = lane >> 5;
    const int row0 = blockIdx.x * 128;
    const int rowA = row0 + wave * 32 + n;

    uint4 xh[8], xl[8];
    const float* xrow = x + (size_t)rowA * DIMD + h * 8;
#pragma unroll
    for (int s = 0; s < 8; ++s) {
        float4 a = *(const float4*)(xrow + s * 16);
        float4 b = *(const float4*)(xrow + s * 16 + 4);
        float f[8] = {a.x, a.y, a.z, a.w, b.x, b.y, b.z, b.w};
        unsigned hi[8], lo[8];
#pragma unroll
        for (int j = 0; j < 8; ++j) {
            hi[j] = bfr(f[j]);
            float hf = __uint_as_float(hi[j] << 16);
            lo[j] = bfr(f[j] - hf);
        }
        xh[s].x = hi[0] | (hi[1] << 16); xh[s].y = hi[2] | (hi[3] << 16);
        xh[s].z = hi[4] | (hi[5] << 16); xh[s].w = hi[6] | (hi[7] << 16);
        xl[s].x = lo[0] | (lo[1] << 16); xl[s].y = lo[2] | (lo[3] << 16);
        xl[s].z = lo[4] | (lo[5] << 16); xl[s].w = lo[6] | (lo[7] << 16);
    }

    float bestv[16], best2[16];
    int   besti[16];
#pragma unroll
    for (int r = 0; r < 16; ++r) { bestv[r] = FLT_MAX; best2[r] = FLT_MAX; besti[r] = 0; }

    for (int chunk = 0; chunk < KCODES / 32; ++chunk) {
        __syncthreads();
        {
            const uint4* sh = ehg + chunk * 512;
            const uint4* sl = elg + chunk * 512;
#pragma unroll
            for (int i = 0; i < 2; ++i) {
                int idx = tid + i * 256;
                Bs[idx]       = sh[idx];
                Bs[512 + idx] = sl[idx];
            }
        }
        float ee_val = enorm[chunk * 32 + n];
        __syncthreads();

        f32x16 acc;
#pragma unroll
        for (int r = 0; r < 16; ++r) acc[r] = 0.f;

#pragma unroll
        for (int s = 0; s < 8; ++s) {
            U8 ah, al, bh, bl;
            ah.u = xh[s]; al.u = xl[s];
            bh.u = Bs[s * 64 + lane];
            bl.u = Bs[512 + s * 64 + lane];
            acc = __builtin_amdgcn_mfma_f32_32x32x16_bf16(ah.s, bh.s, acc, 0, 0, 0);
            acc = __builtin_amdgcn_mfma_f32_32x32x16_bf16(ah.s, bl.s, acc, 0, 0, 0);
            acc = __builtin_amdgcn_mfma_f32_32x32x16_bf16(al.s, bh.s, acc, 0, 0, 0);
        }

        const int nglob = chunk * 32 + n;
#pragma unroll
        for (int r = 0; r < 16; ++r) {
            float d = fmaf(-2.f, acc[r], ee_val);
            bool c1 = d < bestv[r];
            float t = c1 ? bestv[r] : d;
            best2[r] = fminf(best2[r], t);
            besti[r] = c1 ? nglob : besti[r];
            bestv[r] = fminf(bestv[r], d);
        }
    }

#pragma unroll
    for (int m = 1; m <= 16; m <<= 1) {
#pragma unroll
        for (int r = 0; r < 16; ++r) {
            float ov = __shfl_xor(bestv[r], m, 64);
            float o2 = __shfl_xor(best2[r], m, 64);
            int   oi = __shfl_xor(besti[r], m, 64);
            float hi = fmaxf(bestv[r], ov);
            best2[r] = fminf(fminf(best2[r], o2), hi);
            bool take = (ov < bestv[r]) || (ov == bestv[r] && oi < besti[r]);
            bestv[r] = take ? ov : bestv[r];
            besti[r] = take ? oi : besti[r];
        }
    }

    if (n == 0) {
#pragma unroll
        for (int r = 0; r < 16; ++r) {
            int row = row0 + wave * 32 + (r & 3) + 8 * (r >> 2) + 4 * h;
            ind_i[row] = besti[r];
            ind_f[row] = (float)besti[r];
            if (best2[r] - bestv[r] < TAU) {
                int p = atomicAdd(wl_cnt, 1);
                wl[p] = row;
            }
        }
    }
}

// ---------------- exact fp32 re-check for near-tie rows ----------------
__global__ __launch_bounds__(256) void recheck_kernel(
    const float* __restrict__ x, const float* __restrict__ embed,
    const float* __restrict__ enorm, const int* __restrict__ wl,
    const int* __restrict__ wl_cnt, int* __restrict__ ind_i, float* __restrict__ ind_f)
{
    __shared__ float xs[DIMD];
    __shared__ float rv[256];
    __shared__ int   ri[256];
    const int tid = threadIdx.x;
    const int count = *wl_cnt;

    for (int i = blockIdx.x; i < count; i += gridDim.x) {
        const int row = wl[i];
        __syncthreads();
        if (tid < DIMD) xs[tid] = x[(size_t)row * DIMD + tid];
        __syncthreads();

        const float4* xs4 = (const float4*)xs;
        float xn = 0.f;
#pragma unroll 8
        for (int c = 0; c < 32; ++c) {
            float4 v = xs4[c];
            xn += v.x * v.x + v.y * v.y + v.z * v.z + v.w * v.w;
        }

        float bv = FLT_MAX; int bi = 0;
#pragma unroll
        for (int c = 0; c < 4; ++c) {
            int code = tid * 4 + c;
            const float4* er = (const float4*)(embed + (size_t)code * DIMD);
            float acc = 0.f;
#pragma unroll 8
            for (int kk = 0; kk < 32; ++kk) {
                float4 a = xs4[kk];
                float4 b = er[kk];
                acc += a.x * b.x + a.y * b.y + a.z * b.z + a.w * b.w;
            }
            float d = (xn - 2.0f * acc) + enorm[code];
            if (d < bv) { bv = d; bi = code; }
        }
        rv[tid] = bv; ri[tid] = bi;
        __syncthreads();
        for (int s = 128; s > 0; s >>= 1) {
            if (tid < s) {
                if (rv[tid + s] < rv[tid] || (rv[tid + s] == rv[tid] && ri[tid + s] < ri[tid])) {
                    rv[tid] = rv[tid + s]; ri[tid] = ri[tid + s];
                }
            }
            __syncthreads();
        }
        if (tid == 0) { ind_i[row] = ri[0]; ind_f[row] = (float)ri[0]; }
    }
}

// ---------------- histogram of code assignments ----------------
__global__ __launch_bounds__(256) void hist_kernel(
    const int* __restrict__ ind, int* __restrict__ counts)
{
    __shared__ int h[KCODES];
    for (int i = threadIdx.x; i < KCODES; i += 256) h[i] = 0;
    __syncthreads();
    const int base = blockIdx.x * 2048;
    for (int i = threadIdx.x; i < 2048; i += 256) atomicAdd(&h[ind[base + i]], 1);
    __syncthreads();
    for (int i = threadIdx.x; i < KCODES; i += 256) {
        int v = h[i];
        if (v) atomicAdd(&counts[i], v);
    }
}

// ---------------- exclusive prefix scan (1 block) ----------------
__global__ __launch_bounds__(1024) void scan_kernel(
    const int* __restrict__ counts, int* __restrict__ offsets, int* __restrict__ cursor)
{
    __shared__ int s[KCODES];
    const int t = threadIdx.x;
    int my = counts[t];
    s[t] = my;
    __syncthreads();
    for (int d = 1; d < KCODES; d <<= 1) {
        int v = (t >= d) ? s[t - d] : 0;
        __syncthreads();
        s[t] += v;
        __syncthreads();
    }
    int excl = s[t] - my;
    offsets[t] = excl;
    cursor[t]  = excl;
}

// ---------------- permute rows into code buckets + gather quantize ----------------
__global__ __launch_bounds__(256) void permgather_kernel(
    const float* __restrict__ embed, const int* __restrict__ ind,
    int* __restrict__ cursor, int* __restrict__ perm, float* __restrict__ out_q)
{
    const int tid = threadIdx.x;
    const int row = blockIdx.x * 8 + (tid >> 5);
    const int c = tid & 31;
    const int k = ind[row];

    if (c == 0) {
        int pos = atomicAdd(&cursor[k], 1);
        perm[pos] = row;
    }
    float4 e = *(const float4*)(embed + (size_t)k * DIMD + c * 4);
    *(float4*)(out_q + (size_t)row * DIMD + c * 4) = e;
}

// ---------------- per-code segmented sum (no atomics) ----------------
__global__ __launch_bounds__(256) void segsum_kernel(
    const float* __restrict__ x, const int* __restrict__ perm,
    const int* __restrict__ offsets, const int* __restrict__ counts,
    float* __restrict__ embed_sum)
{
    __shared__ float4 red[8][32];
    const int k = blockIdx.x;
    const int start = offsets[k];
    const int cnt = counts[k];
    const int g = threadIdx.x >> 5;
    const int c = threadIdx.x & 31;

    float4 acc = {0.f, 0.f, 0.f, 0.f};
    for (int j = g; j < cnt; j += 8) {
        int r = perm[start + j];
        float4 v = *(const float4*)(x + (size_t)r * DIMD + c * 4);
        acc.x += v.x; acc.y += v.y; acc.z += v.z; acc.w += v.w;
    }
    red[g][c] = acc;
    __syncthreads();
    for (int s = 4; s >= 1; s >>= 1) {
        if (g < s) {
            float4 o = red[g + s][c];
            red[g][c].x += o.x; red[g][c].y += o.y;
            red[g][c].z += o.z; red[g][c].w += o.w;
        }
        __syncthreads();
    }
    if (g == 0) {
        *(float4*)(embed_sum + (size_t)k * DIMD + c * 4) = red[0][c];
    }
}

// ---------------- cluster_size EMA + total + smoothed ----------------
__global__ __launch_bounds__(1024) void cluster_kernel(
    const float* __restrict__ cluster_size, const int* __restrict__ counts,
    float* __restrict__ out_cs, float* __restrict__ smoothed)
{
    __shared__ float red[1024];
    const int t = threadIdx.x;
    float cs = cluster_size[t] * 0.99f + (float)counts[t] * 0.01f;
    out_cs[t] = cs;
    red[t] = cs;
    __syncthreads();
    for (int s = 512; s > 0; s >>= 1) {
        if (t < s) red[t] += red[t + s];
        __syncthreads();
    }
    float total = red[0];
    smoothed[t] = (cs + 1e-6f) / (total + 1e-6f * (float)KCODES) * total;
}

// ---------------- embed_avg EMA + embed_new ----------------
__global__ void embed_kernel(
    const float* __restrict__ embed_avg, const float* __restrict__ embed_sum,
    const float* __restrict__ smoothed, float* __restrict__ out_ea,
    float* __restrict__ out_en)
{
    int i = blockIdx.x * blockDim.x + threadIdx.x;
    if (i < KCODES * DIMD) {
        float ea = embed_avg[i] * 0.99f + embed_sum[i] * 0.01f;
        out_ea[i] = ea;
        out_en[i] = ea / smoothed[i >> 7];
    }
}

extern "C" void kernel_launch(void* const* d_in, const int* in_sizes, int n_in,
                              void* d_out, int out_size, void* d_ws, size_t ws_size,
                              hipStream_t stream) {
    const float* x            = (const float*)d_in[0];
    const float* embed        = (const float*)d_in[1];
    const float* cluster_size = (const float*)d_in[2];
    const float* embed_avg    = (const float*)d_in[3];

    float* out     = (float*)d_out;
    float* out_q   = out;                       // [65536*128]
    float* out_ind = out + 8388608;             // [65536]
    float* out_cs  = out + 8454144;             // [1024]
    float* out_ea  = out + 8455168;             // [1024*128]
    float* out_en  = out + 8586240;             // [1024*128]

    char* ws = (char*)d_ws;
    int*   ind_i     = (int*)(ws + 0);          // 256 KB
    float* enorm     = (float*)(ws + 262144);   // 4 KB
    int*   countsI   = (int*)(ws + 266240);     // 4 KB  \ zeroed together
    int*   wl_cnt    = (int*)(ws + 270336);     // 4 KB  /
    int*   offsets   = (int*)(ws + 274432);     // 4 KB
    int*   cursor    = (int*)(ws + 278528);     // 4 KB
    float* smoothed  = (float*)(ws + 282624);   // 4 KB
    int*   perm      = (int*)(ws + 286720);     // 256 KB
    int*   wl        = (int*)(ws + 548864);     // 256 KB
    uint4* ehg       = (uint4*)(ws + 811008);   // 256 KB (dead after argmin)
    uint4* elg       = (uint4*)(ws + 1073152);  // 256 KB (dead after argmin)
    float* embed_sum = (float*)(ws + 811008);   // 512 KB — OVERLAPS ehg+elg (disjoint lifetime)

    hipMemsetAsync(countsI, 0, 8192, stream);   // countsI + wl_cnt

    enorm_kernel<<<4, 256, 0, stream>>>(embed, enorm);
    preconvert_kernel<<<64, 256, 0, stream>>>(embed, ehg, elg);
    argmin_mfma<<<NROWS / 128, 256, 0, stream>>>(x, ehg, elg, enorm, ind_i, out_ind, wl, wl_cnt);
    recheck_kernel<<<256, 256, 0, stream>>>(x, embed, enorm, wl, wl_cnt, ind_i, out_ind);
    hist_kernel<<<32, 256, 0, stream>>>(ind_i, countsI);
    scan_kernel<<<1, 1024, 0, stream>>>(countsI, offsets, cursor);
    permgather_kernel<<<NROWS / 8, 256, 0, stream>>>(embed, ind_i, cursor, perm, out_q);
    segsum_kernel<<<KCODES, 256, 0, stream>>>(x, perm, offsets, countsI, embed_sum);
    cluster_kernel<<<1, 1024, 0, stream>>>(cluster_size, countsI, out_cs, smoothed);
    embed_kernel<<<(KCODES * DIMD + 255) / 256, 256, 0, stream>>>(
        embed_avg, embed_sum, smoothed, out_ea, out_en);
}

// Round 4
// 293.139 us; speedup vs baseline: 2.6871x; 1.3842x over previous
//
#include <hip/hip_runtime.h>
#include <float.h>

#define DIMD   128
#define KCODES 1024
#define NROWS  65536
#define TAU    0.05f
#define SEG_R  8     // rows per segsum group

typedef __attribute__((ext_vector_type(8)))  short short8;
typedef __attribute__((ext_vector_type(16))) float f32x16;

union U8 { uint4 u; short8 s; };

// round-to-nearest-even float -> bf16 (as uint16 in low bits)
__device__ __forceinline__ unsigned bfr(float f) {
    unsigned u = __float_as_uint(f);
    return (u + 0x7fffu + ((u >> 16) & 1u)) >> 16;
}

// ---------------- embed row norms: |e_k|^2 ----------------
__global__ void enorm_kernel(const float* __restrict__ embed, float* __restrict__ enorm) {
    int k = blockIdx.x * blockDim.x + threadIdx.x;
    if (k < KCODES) {
        const float4* e = (const float4*)(embed + (size_t)k * DIMD);
        float s = 0.f;
#pragma unroll
        for (int c = 0; c < DIMD / 4; ++c) {
            float4 v = e[c];
            s += v.x * v.x + v.y * v.y + v.z * v.z + v.w * v.w;
        }
        enorm[k] = s;
    }
}

// ---------------- pre-convert codebook to fragment-major bf16 hi/lo ----------------
__global__ __launch_bounds__(256) void preconvert_kernel(
    const float* __restrict__ embed, uint4* __restrict__ ehg, uint4* __restrict__ elg)
{
    int t = blockIdx.x * 256 + threadIdx.x;     // 0..16383
    int chunk = t >> 9;
    int s = (t >> 6) & 7;
    int L = t & 63;
    const float* src = embed + ((size_t)(chunk * 32 + (L & 31)) * DIMD) + s * 16 + (L >> 5) * 8;
    float4 a = *(const float4*)src;
    float4 b = *(const float4*)(src + 4);
    float f[8] = {a.x, a.y, a.z, a.w, b.x, b.y, b.z, b.w};
    unsigned hi[8], lo[8];
#pragma unroll
    for (int j = 0; j < 8; ++j) {
        hi[j] = bfr(f[j]);
        float hf = __uint_as_float(hi[j] << 16);
        lo[j] = bfr(f[j] - hf);
    }
    uint4 H, Lw;
    H.x = hi[0] | (hi[1] << 16); H.y = hi[2] | (hi[3] << 16);
    H.z = hi[4] | (hi[5] << 16); H.w = hi[6] | (hi[7] << 16);
    Lw.x = lo[0] | (lo[1] << 16); Lw.y = lo[2] | (lo[3] << 16);
    Lw.z = lo[4] | (lo[5] << 16); Lw.w = lo[6] | (lo[7] << 16);
    ehg[t] = H;
    elg[t] = Lw;
}

// ---------------- fused MFMA distance + argmin (top-2 tracked) ----------------
__global__ __launch_bounds__(256, 2) void argmin_mfma(
    const float* __restrict__ x, const uint4* __restrict__ ehg, const uint4* __restrict__ elg,
    const float* __restrict__ enorm, int* __restrict__ ind_i, float* __restrict__ ind_f,
    int* __restrict__ wl, int* __restrict__ wl_cnt)
{
    __shared__ uint4 Bs[1024];

    const int tid  = threadIdx.x;
    const int wave = tid >> 6;
    const int lane = tid & 63;
    const int n    = lane & 31;
    const int h    = lane >> 5;
    const int row0 = blockIdx.x * 128;
    const int rowA = row0 + wave * 32 + n;

    uint4 xh[8], xl[8];
    const float* xrow = x + (size_t)rowA * DIMD + h * 8;
#pragma unroll
    for (int s = 0; s < 8; ++s) {
        float4 a = *(const float4*)(xrow + s * 16);
        float4 b = *(const float4*)(xrow + s * 16 + 4);
        float f[8] = {a.x, a.y, a.z, a.w, b.x, b.y, b.z, b.w};
        unsigned hi[8], lo[8];
#pragma unroll
        for (int j = 0; j < 8; ++j) {
            hi[j] = bfr(f[j]);
            float hf = __uint_as_float(hi[j] << 16);
            lo[j] = bfr(f[j] - hf);
        }
        xh[s].x = hi[0] | (hi[1] << 16); xh[s].y = hi[2] | (hi[3] << 16);
        xh[s].z = hi[4] | (hi[5] << 16); xh[s].w = hi[6] | (hi[7] << 16);
        xl[s].x = lo[0] | (lo[1] << 16); xl[s].y = lo[2] | (lo[3] << 16);
        xl[s].z = lo[4] | (lo[5] << 16); xl[s].w = lo[6] | (lo[7] << 16);
    }

    float bestv[16], best2[16];
    int   besti[16];
#pragma unroll
    for (int r = 0; r < 16; ++r) { bestv[r] = FLT_MAX; best2[r] = FLT_MAX; besti[r] = 0; }

    for (int chunk = 0; chunk < KCODES / 32; ++chunk) {
        __syncthreads();
        {
            const uint4* sh = ehg + chunk * 512;
            const uint4* sl = elg + chunk * 512;
#pragma unroll
            for (int i = 0; i < 2; ++i) {
                int idx = tid + i * 256;
                Bs[idx]       = sh[idx];
                Bs[512 + idx] = sl[idx];
            }
        }
        float ee_val = enorm[chunk * 32 + n];
        __syncthreads();

        f32x16 acc;
#pragma unroll
        for (int r = 0; r < 16; ++r) acc[r] = 0.f;

#pragma unroll
        for (int s = 0; s < 8; ++s) {
            U8 ah, al, bh, bl;
            ah.u = xh[s]; al.u = xl[s];
            bh.u = Bs[s * 64 + lane];
            bl.u = Bs[512 + s * 64 + lane];
            acc = __builtin_amdgcn_mfma_f32_32x32x16_bf16(ah.s, bh.s, acc, 0, 0, 0);
            acc = __builtin_amdgcn_mfma_f32_32x32x16_bf16(ah.s, bl.s, acc, 0, 0, 0);
            acc = __builtin_amdgcn_mfma_f32_32x32x16_bf16(al.s, bh.s, acc, 0, 0, 0);
        }

        const int nglob = chunk * 32 + n;
#pragma unroll
        for (int r = 0; r < 16; ++r) {
            float d = fmaf(-2.f, acc[r], ee_val);
            bool c1 = d < bestv[r];
            float t = c1 ? bestv[r] : d;
            best2[r] = fminf(best2[r], t);
            besti[r] = c1 ? nglob : besti[r];
            bestv[r] = fminf(bestv[r], d);
        }
    }

#pragma unroll
    for (int m = 1; m <= 16; m <<= 1) {
#pragma unroll
        for (int r = 0; r < 16; ++r) {
            float ov = __shfl_xor(bestv[r], m, 64);
            float o2 = __shfl_xor(best2[r], m, 64);
            int   oi = __shfl_xor(besti[r], m, 64);
            float hi = fmaxf(bestv[r], ov);
            best2[r] = fminf(fminf(best2[r], o2), hi);
            bool take = (ov < bestv[r]) || (ov == bestv[r] && oi < besti[r]);
            bestv[r] = take ? ov : bestv[r];
            besti[r] = take ? oi : besti[r];
        }
    }

    if (n == 0) {
#pragma unroll
        for (int r = 0; r < 16; ++r) {
            int row = row0 + wave * 32 + (r & 3) + 8 * (r >> 2) + 4 * h;
            ind_i[row] = besti[r];
            ind_f[row] = (float)besti[r];
            if (best2[r] - bestv[r] < TAU) {
                int p = atomicAdd(wl_cnt, 1);
                wl[p] = row;
            }
        }
    }
}

// ---------------- exact fp32 re-check for near-tie rows ----------------
__global__ __launch_bounds__(256) void recheck_kernel(
    const float* __restrict__ x, const float* __restrict__ embed,
    const float* __restrict__ enorm, const int* __restrict__ wl,
    const int* __restrict__ wl_cnt, int* __restrict__ ind_i, float* __restrict__ ind_f)
{
    __shared__ float xs[DIMD];
    __shared__ float rv[256];
    __shared__ int   ri[256];
    const int tid = threadIdx.x;
    const int count = *wl_cnt;

    for (int i = blockIdx.x; i < count; i += gridDim.x) {
        const int row = wl[i];
        __syncthreads();
        if (tid < DIMD) xs[tid] = x[(size_t)row * DIMD + tid];
        __syncthreads();

        const float4* xs4 = (const float4*)xs;
        float xn = 0.f;
#pragma unroll 8
        for (int c = 0; c < 32; ++c) {
            float4 v = xs4[c];
            xn += v.x * v.x + v.y * v.y + v.z * v.z + v.w * v.w;
        }

        float bv = FLT_MAX; int bi = 0;
#pragma unroll
        for (int c = 0; c < 4; ++c) {
            int code = tid * 4 + c;
            const float4* er = (const float4*)(embed + (size_t)code * DIMD);
            float acc = 0.f;
#pragma unroll 8
            for (int kk = 0; kk < 32; ++kk) {
                float4 a = xs4[kk];
                float4 b = er[kk];
                acc += a.x * b.x + a.y * b.y + a.z * b.z + a.w * b.w;
            }
            float d = (xn - 2.0f * acc) + enorm[code];
            if (d < bv) { bv = d; bi = code; }
        }
        rv[tid] = bv; ri[tid] = bi;
        __syncthreads();
        for (int s = 128; s > 0; s >>= 1) {
            if (tid < s) {
                if (rv[tid + s] < rv[tid] || (rv[tid + s] == rv[tid] && ri[tid + s] < ri[tid])) {
                    rv[tid] = rv[tid + s]; ri[tid] = ri[tid + s];
                }
            }
            __syncthreads();
        }
        if (tid == 0) { ind_i[row] = ri[0]; ind_f[row] = (float)ri[0]; }
    }
}

// ---------------- histogram of code assignments ----------------
__global__ __launch_bounds__(256) void hist_kernel(
    const int* __restrict__ ind, int* __restrict__ counts)
{
    __shared__ int h[KCODES];
    for (int i = threadIdx.x; i < KCODES; i += 256) h[i] = 0;
    __syncthreads();
    const int base = blockIdx.x * 2048;
    for (int i = threadIdx.x; i < 2048; i += 256) atomicAdd(&h[ind[base + i]], 1);
    __syncthreads();
    for (int i = threadIdx.x; i < KCODES; i += 256) {
        int v = h[i];
        if (v) atomicAdd(&counts[i], v);
    }
}

// ---------------- exclusive prefix scan (1 block) ----------------
__global__ __launch_bounds__(1024) void scan_kernel(
    const int* __restrict__ counts, int* __restrict__ cursor)
{
    __shared__ int s[KCODES];
    const int t = threadIdx.x;
    int my = counts[t];
    s[t] = my;
    __syncthreads();
    for (int d = 1; d < KCODES; d <<= 1) {
        int v = (t >= d) ? s[t - d] : 0;
        __syncthreads();
        s[t] += v;
        __syncthreads();
    }
    cursor[t] = s[t] - my;
}

// ---------------- permute rows into code buckets + gather quantize ----------------
__global__ __launch_bounds__(256) void permgather_kernel(
    const float* __restrict__ embed, const int* __restrict__ ind,
    int* __restrict__ cursor, int* __restrict__ perm, int* __restrict__ codes,
    float* __restrict__ out_q)
{
    const int tid = threadIdx.x;
    const int row = blockIdx.x * 8 + (tid >> 5);
    const int c = tid & 31;
    const int k = ind[row];

    if (c == 0) {
        int pos = atomicAdd(&cursor[k], 1);
        perm[pos] = row;
        codes[pos] = k;
    }
    float4 e = *(const float4*)(embed + (size_t)k * DIMD + c * 4);
    *(float4*)(out_q + (size_t)row * DIMD + c * 4) = e;
}

// ---------------- balanced chunked segmented sum (boundary atomics) ----------------
__global__ __launch_bounds__(256) void segsum_kernel(
    const float* __restrict__ x, const int* __restrict__ perm,
    const int* __restrict__ codes, float* __restrict__ embed_sum)
{
    const int g = (blockIdx.x * 256 + threadIdx.x) >> 5;   // group id, 0..8191
    const int c = threadIdx.x & 31;                        // lane owns cols 4c..4c+3
    const int base = g * SEG_R;

    float4 acc = {0.f, 0.f, 0.f, 0.f};
    int curk = codes[base];
#pragma unroll
    for (int j = 0; j < SEG_R; ++j) {
        int r = perm[base + j];
        int k = codes[base + j];
        float4 v = *(const float4*)(x + (size_t)r * DIMD + c * 4);
        if (k != curk) {
            float* dst = embed_sum + (size_t)curk * DIMD + c * 4;
            atomicAdd(dst + 0, acc.x);
            atomicAdd(dst + 1, acc.y);
            atomicAdd(dst + 2, acc.z);
            atomicAdd(dst + 3, acc.w);
            acc = v;
            curk = k;
        } else {
            acc.x += v.x; acc.y += v.y; acc.z += v.z; acc.w += v.w;
        }
    }
    float* dst = embed_sum + (size_t)curk * DIMD + c * 4;
    atomicAdd(dst + 0, acc.x);
    atomicAdd(dst + 1, acc.y);
    atomicAdd(dst + 2, acc.z);
    atomicAdd(dst + 3, acc.w);
}

// ---------------- cluster_size EMA + total + smoothed ----------------
__global__ __launch_bounds__(1024) void cluster_kernel(
    const float* __restrict__ cluster_size, const int* __restrict__ counts,
    float* __restrict__ out_cs, float* __restrict__ smoothed)
{
    __shared__ float red[1024];
    const int t = threadIdx.x;
    float cs = cluster_size[t] * 0.99f + (float)counts[t] * 0.01f;
    out_cs[t] = cs;
    red[t] = cs;
    __syncthreads();
    for (int s = 512; s > 0; s >>= 1) {
        if (t < s) red[t] += red[t + s];
        __syncthreads();
    }
    float total = red[0];
    smoothed[t] = (cs + 1e-6f) / (total + 1e-6f * (float)KCODES) * total;
}

// ---------------- embed_avg EMA + embed_new ----------------
__global__ void embed_kernel(
    const float* __restrict__ embed_avg, const float* __restrict__ embed_sum,
    const float* __restrict__ smoothed, float* __restrict__ out_ea,
    float* __restrict__ out_en)
{
    int i = blockIdx.x * blockDim.x + threadIdx.x;
    if (i < KCODES * DIMD) {
        float ea = embed_avg[i] * 0.99f + embed_sum[i] * 0.01f;
        out_ea[i] = ea;
        out_en[i] = ea / smoothed[i >> 7];
    }
}

extern "C" void kernel_launch(void* const* d_in, const int* in_sizes, int n_in,
                              void* d_out, int out_size, void* d_ws, size_t ws_size,
                              hipStream_t stream) {
    const float* x            = (const float*)d_in[0];
    const float* embed        = (const float*)d_in[1];
    const float* cluster_size = (const float*)d_in[2];
    const float* embed_avg    = (const float*)d_in[3];

    float* out     = (float*)d_out;
    float* out_q   = out;                       // [65536*128]
    float* out_ind = out + 8388608;             // [65536]
    float* out_cs  = out + 8454144;             // [1024]
    float* out_ea  = out + 8455168;             // [1024*128]
    float* out_en  = out + 8586240;             // [1024*128]

    char* ws = (char*)d_ws;
    int*   ind_i     = (int*)(ws + 0);          // 256 KB
    float* enorm     = (float*)(ws + 262144);   // 4 KB
    int*   countsI   = (int*)(ws + 266240);     // 4 KB  \ zeroed together
    int*   wl_cnt    = (int*)(ws + 270336);     // 4 KB  /
    int*   cursor    = (int*)(ws + 274432);     // 4 KB
    float* smoothed  = (float*)(ws + 278528);   // 4 KB
    int*   perm      = (int*)(ws + 286720);     // 256 KB
    int*   wl        = (int*)(ws + 548864);     // 256 KB (dead after recheck)
    int*   codes     = (int*)(ws + 548864);     // 256 KB — ALIASES wl (disjoint lifetime)
    uint4* ehg       = (uint4*)(ws + 811008);   // 256 KB (dead after argmin)
    uint4* elg       = (uint4*)(ws + 1073152);  // 256 KB (dead after argmin)
    float* embed_sum = (float*)(ws + 811008);   // 512 KB — ALIASES ehg+elg (disjoint lifetime)

    hipMemsetAsync(countsI, 0, 8192, stream);   // countsI + wl_cnt

    enorm_kernel<<<4, 256, 0, stream>>>(embed, enorm);
    preconvert_kernel<<<64, 256, 0, stream>>>(embed, ehg, elg);
    argmin_mfma<<<NROWS / 128, 256, 0, stream>>>(x, ehg, elg, enorm, ind_i, out_ind, wl, wl_cnt);
    recheck_kernel<<<256, 256, 0, stream>>>(x, embed, enorm, wl, wl_cnt, ind_i, out_ind);
    hist_kernel<<<32, 256, 0, stream>>>(ind_i, countsI);
    scan_kernel<<<1, 1024, 0, stream>>>(countsI, cursor);
    // ehg/elg now dead — zero the aliased embed_sum region before atomic accumulation
    hipMemsetAsync(embed_sum, 0, 524288, stream);
    permgather_kernel<<<NROWS / 8, 256, 0, stream>>>(embed, ind_i, cursor, perm, codes, out_q);
    segsum_kernel<<<(NROWS / SEG_R) * 32 / 256, 256, 0, stream>>>(x, perm, codes, embed_sum);
    cluster_kernel<<<1, 1024, 0, stream>>>(cluster_size, countsI, out_cs, smoothed);
    embed_kernel<<<(KCODES * DIMD + 255) / 256, 256, 0, stream>>>(
        embed_avg, embed_sum, smoothed, out_ea, out_en);
}